// Round 5
// baseline (435.326 us; speedup 1.0000x reference)
//
#include <hip/hip_runtime.h>

// B=8, H=W=256, I_DIM=64, K_DIM=64 (hd_k=32), V_DIM=32 (hd_v=16), O_DIM=64
// NH=2, unfold: p=7, stride=21, dilation=4, npw=12 -> S=144 patches
// Sampled grid 84x84; each sampled pixel belongs to exactly ONE patch.
#define BB 8
#define HH 256
#define CIN 64
#define NPW 12
#define SPP 144
#define PP 49
#define PDIM 7
#define STRIDE 21
#define DIL 4
#define NS 84
#define HDK 32
#define HDV 16
#define RS 52    // bf16 row stride (shorts): 104 B rows, 8 B-aligned ushort4 at x4 offsets
#define WTS 196  // Wt row stride (192 rows + 4 pad), keeps ushort4 8B-aligned

static __device__ __forceinline__ unsigned short f2bf(float f) {
  union { float f; unsigned u; } v; v.f = f;
  unsigned r = (v.u + 0x7fffu + ((v.u >> 16) & 1u)) >> 16;
  return (unsigned short)r;
}
static __device__ __forceinline__ float bf2f(unsigned short h) {
  union { unsigned u; float f; } v; v.u = ((unsigned)h) << 16;
  return v.f;
}

// ---------------------------------------------------------------------------
// Kernel 1: one block per (b, patch), both heads in parallel per phase.
// All weights staged in LDS (transposed bf16) -> phase 1/6 inner loops are
// pure LDS+VALU (no per-iteration global loads). 5 barriers. 58.4 KB LDS,
// 2 blocks/CU.
// ---------------------------------------------------------------------------
__global__ __launch_bounds__(256, 2) void k1_fused(
    const float* __restrict__ x1, const float* __restrict__ x2,
    const float* __restrict__ Wk, const float* __restrict__ bk,
    const float* __restrict__ Wv, const float* __restrict__ bv,
    const float* __restrict__ Wp, float* __restrict__ P)
{
  // kv rows (bf16): 0..63 K1 (ch=row), 64..127 K2, 128..159 V1, 160..191 V2
  __shared__ unsigned short kv[192][RS];                  // 19968 B
  __shared__ union UU {
    struct {                                              // phases 0-1
      unsigned short xs[2][CIN][RS];                      // 13312
      unsigned short Wt[CIN][WTS];                        // 25088  W^T[c][row]
    } p0;                                                 // 38400
    struct {                                              // phases 2+
      unsigned short kkb[2][49][RS];                      // 10192 (bf16 logits)
      unsigned short O[64][RS];                           // 6656  (bf16 o-ch)
      float cmax[2][49], csum[2][49];                     // 1568 stats
      float rmax[2][49], rsum[2][49];
      unsigned short Wpt[64][68];                         // 8704  Wp^T[l][oc]
    } p1;                                                 // 27120
  } u;                                                    // union = 38400 B

  const int tid = threadIdx.x;
  const int blk = blockIdx.x;
  const int b  = blk / SPP;
  const int s  = blk % SPP;
  const int pi = s / NPW, pj = s % NPW;
  const int h0 = pi * STRIDE, w0 = pj * STRIDE;

  // ---- phase 0a: stage weights transposed bf16: Wt[c][row], rows 0..127 Wk,
  //      128..191 Wv. Coalesced global reads (consecutive i -> consecutive c).
  for (int i = tid; i < 192 * 64; i += 256) {
    int row = i >> 6, c = i & 63;
    float w = (row < 128) ? Wk[row * 64 + c] : Wv[(row - 128) * 64 + c];
    u.p0.Wt[c][row] = f2bf(w);
  }
  // ---- phase 0b: gather x tiles into LDS (bf16) ----
  for (int i = tid; i < 2 * CIN * PP; i += 256) {
    int src = i / (CIN * PP);
    int r = i - src * (CIN * PP);
    int c = r / PP, t = r - c * PP;
    int ph = t / PDIM, pw = t - ph * PDIM;
    const float* xp = src ? x2 : x1;
    float v = xp[(((size_t)b * CIN + c) * HH + (h0 + ph * DIL)) * HH + (w0 + pw * DIL)];
    u.p0.xs[src][c][t] = f2bf(v);
  }
  __syncthreads();

  // ---- phase 1: projections 192 rows x 49 px, 4x4 register tiles,
  //      weights AND x from LDS (2x ds_read_b64 + 16 FMA per c) ----
  for (int task = tid; task < 48 * 13; task += 256) {
    int g = task / 13, tg = task % 13;
    int row0 = g * 4, t0 = tg * 4;
    int src = (row0 < 64) ? 0 : (row0 < 128 ? 1 : (row0 < 160 ? 0 : 1));
    float bias[4];
    if (row0 < 128) {
      #pragma unroll
      for (int i = 0; i < 4; i++) bias[i] = bk[row0 + i];
    } else {
      #pragma unroll
      for (int i = 0; i < 4; i++) bias[i] = bv[row0 - 128 + i];
    }
    const unsigned short* xsrc = &u.p0.xs[src][0][0];
    float acc[4][4];
    #pragma unroll
    for (int i = 0; i < 4; i++)
      #pragma unroll
      for (int j = 0; j < 4; j++) acc[i][j] = 0.f;
    for (int c = 0; c < 64; c++) {
      ushort4 w4 = *(const ushort4*)&u.p0.Wt[c][row0];
      ushort4 x4 = *(const ushort4*)&xsrc[c * RS + t0];
      float wv[4] = { bf2f(w4.x), bf2f(w4.y), bf2f(w4.z), bf2f(w4.w) };
      float xv[4] = { bf2f(x4.x), bf2f(x4.y), bf2f(x4.z), bf2f(x4.w) };
      #pragma unroll
      for (int i = 0; i < 4; i++)
        #pragma unroll
        for (int j = 0; j < 4; j++) acc[i][j] += wv[i] * xv[j];
    }
    #pragma unroll
    for (int i = 0; i < 4; i++)
      #pragma unroll
      for (int j = 0; j < 4; j++)
        if (t0 + j < PP) kv[row0 + i][t0 + j] = f2bf(acc[i][j] + bias[i]);
  }
  __syncthreads();  // p0 dead; union becomes kkb/O/stats/Wpt

  const float scale = 0.17677669529663687f;  // 1/sqrt(32)

  // ---- phase 2: logits kkb[n][x][y], both heads; idle threads stage Wp^T ----
  if (tid < 182) {
    int n = tid / 91;
    int r = tid % 91;
    int xg = r / 7, yg = r % 7;
    int x0 = xg * 4, y0 = yg * 7;
    float acc[4][7];
    #pragma unroll
    for (int i = 0; i < 4; i++)
      #pragma unroll
      for (int j = 0; j < 7; j++) acc[i][j] = 0.f;
    for (int d = 0; d < HDK; d++) {
      const unsigned short* k1r = kv[n * HDK + d];
      const unsigned short* k2r = kv[64 + n * HDK + d];
      ushort4 a4 = *(const ushort4*)&k1r[x0];
      float av[4] = { bf2f(a4.x), bf2f(a4.y), bf2f(a4.z), bf2f(a4.w) };
      float bvv[7];
      #pragma unroll
      for (int j = 0; j < 7; j++) bvv[j] = bf2f(k2r[y0 + j]);
      #pragma unroll
      for (int i = 0; i < 4; i++)
        #pragma unroll
        for (int j = 0; j < 7; j++) acc[i][j] += av[i] * bvv[j];
    }
    #pragma unroll
    for (int i = 0; i < 4; i++)
      if (x0 + i < 49)
        #pragma unroll
        for (int j = 0; j < 7; j++)
          u.p1.kkb[n][x0 + i][y0 + j] = f2bf(acc[i][j] * scale);
  } else {
    // stage Wp transposed: Wpt[l][oc] = Wp[oc*64+l], 74 threads x ~55 iters
    for (int i = tid - 182; i < 64 * 64; i += 74) {
      int oc = i >> 6, l = i & 63;
      u.p1.Wpt[l][oc] = f2bf(Wp[oc * 64 + l]);
    }
  }
  __syncthreads();

  // ---- phase 3: softmax stats, both heads: 2 x (49 col + 49 row) ----
  if (tid < 196) {
    int n = tid / 98;
    int r = tid % 98;
    int isRow = r >= 49;
    int j = r - (isRow ? 49 : 0);
    float m = -1e30f;
    for (int k = 0; k < 49; k++) {
      float v = bf2f(isRow ? u.p1.kkb[n][j][k] : u.p1.kkb[n][k][j]);
      m = fmaxf(m, v);
    }
    float sm = 0.f;
    for (int k = 0; k < 49; k++) {
      float v = bf2f(isRow ? u.p1.kkb[n][j][k] : u.p1.kkb[n][k][j]);
      sm += __expf(v - m);
    }
    if (isRow) { u.p1.rmax[n][j] = m; u.p1.rsum[n][j] = 1.0f / sm; }
    else       { u.p1.cmax[n][j] = m; u.p1.csum[n][j] = 1.0f / sm; }
  }
  __syncthreads();

  // ---- phase 5: AV with inline exp, both heads+sides ----
  if (tid < 208) {
    int n = tid / 104;
    int r = tid % 104;
    int side = r / 52;
    int r2 = r % 52;
    int dg = r2 / 13, tg = r2 % 13;
    int d0 = dg * 4, t0 = tg * 4;
    int tc[4];
    #pragma unroll
    for (int j = 0; j < 4; j++) tc[j] = min(t0 + j, 48);
    float acc[4][4];
    #pragma unroll
    for (int i = 0; i < 4; i++)
      #pragma unroll
      for (int j = 0; j < 4; j++) acc[i][j] = 0.f;
    if (side == 0) {
      float cm[4];
      #pragma unroll
      for (int j = 0; j < 4; j++) cm[j] = u.p1.cmax[n][tc[j]];
      for (int x = 0; x < 49; x++) {
        ushort4 k4 = *(const ushort4*)&u.p1.kkb[n][x][t0];
        float e[4] = { __expf(bf2f(k4.x) - cm[0]), __expf(bf2f(k4.y) - cm[1]),
                       __expf(bf2f(k4.z) - cm[2]), __expf(bf2f(k4.w) - cm[3]) };
        #pragma unroll
        for (int i = 0; i < 4; i++) {
          float vv = bf2f(kv[128 + n * HDV + d0 + i][x]);
          acc[i][0] += vv * e[0]; acc[i][1] += vv * e[1];
          acc[i][2] += vv * e[2]; acc[i][3] += vv * e[3];
        }
      }
      #pragma unroll
      for (int i = 0; i < 4; i++)
        #pragma unroll
        for (int j = 0; j < 4; j++)
          if (t0 + j < 49)
            u.p1.O[n * HDV + d0 + i][t0 + j] = f2bf(acc[i][j] * u.p1.csum[n][t0 + j]);
    } else {
      float rm[4];
      #pragma unroll
      for (int j = 0; j < 4; j++) rm[j] = u.p1.rmax[n][tc[j]];
      for (int y = 0; y < 49; y++) {
        float e[4];
        #pragma unroll
        for (int j = 0; j < 4; j++)
          e[j] = __expf(bf2f(u.p1.kkb[n][tc[j]][y]) - rm[j]);
        #pragma unroll
        for (int i = 0; i < 4; i++) {
          float vv = bf2f(kv[160 + n * HDV + d0 + i][y]);
          acc[i][0] += vv * e[0]; acc[i][1] += vv * e[1];
          acc[i][2] += vv * e[2]; acc[i][3] += vv * e[3];
        }
      }
      #pragma unroll
      for (int i = 0; i < 4; i++)
        #pragma unroll
        for (int j = 0; j < 4; j++)
          if (t0 + j < 49)
            u.p1.O[32 + n * HDV + d0 + i][t0 + j] = f2bf(acc[i][j] * u.p1.rsum[n][t0 + j]);
    }
  }
  __syncthreads();

  // ---- phase 6: full out-proj from LDS. P[oc][t] = sum_l Wpt[l][oc]*O[l][t]
  if (tid < 208) {
    int ocg = tid / 13, tg = tid % 13;   // 16 x 13
    int oc0 = ocg * 4, t0 = tg * 4;
    float acc[4][4];
    #pragma unroll
    for (int i = 0; i < 4; i++)
      #pragma unroll
      for (int j = 0; j < 4; j++) acc[i][j] = 0.f;
    for (int l = 0; l < 64; l++) {
      ushort4 w4 = *(const ushort4*)&u.p1.Wpt[l][oc0];
      ushort4 o4 = *(const ushort4*)&u.p1.O[l][t0];
      float wv[4] = { bf2f(w4.x), bf2f(w4.y), bf2f(w4.z), bf2f(w4.w) };
      float ov[4] = { bf2f(o4.x), bf2f(o4.y), bf2f(o4.z), bf2f(o4.w) };
      #pragma unroll
      for (int i = 0; i < 4; i++)
        #pragma unroll
        for (int j = 0; j < 4; j++) acc[i][j] += wv[i] * ov[j];
    }
    #pragma unroll
    for (int i = 0; i < 4; i++) {
      #pragma unroll
      for (int j = 0; j < 4; j++) {
        int t = t0 + j;
        if (t < 49) {
          int ph = t / 7, pw = t - ph * 7;
          P[(((size_t)b * 64 + (oc0 + i)) * NS + (pi * 7 + ph)) * NS + (pj * 7 + pw)] =
              acc[i][j];
        }
      }
    }
  }
}

// ---------------------------------------------------------------------------
// Kernel 2: merge. out[b][oc][h][w] = bp[oc] + (sampled ? P : 0). float4.
// ---------------------------------------------------------------------------
__global__ __launch_bounds__(256) void k2_merge(
    const float* __restrict__ P, const float* __restrict__ bp,
    float* __restrict__ out)
{
  __shared__ float bps[64];
  __shared__ int wsmap[256];
  const int tid = threadIdx.x;
  const int b = blockIdx.x / HH, h = blockIdx.x % HH;
  if (tid < 64) bps[tid] = bp[tid];
  {
    int w = tid, wsv = -1;
    for (int pj = 0; pj < NPW; pj++) {
      int r = w - pj * STRIDE;
      if (r >= 0 && r <= (PDIM - 1) * DIL && (r % DIL) == 0) { wsv = pj * PDIM + r / DIL; break; }
    }
    wsmap[tid] = wsv;
  }
  int hs = -1;
  for (int pi = 0; pi < NPW; pi++) {
    int r = h - pi * STRIDE;
    if (r >= 0 && r <= (PDIM - 1) * DIL && (r % DIL) == 0) { hs = pi * PDIM + r / DIL; break; }
  }
  __syncthreads();

  const int wq = tid & 63;   // float4 column
  const int ocq = tid >> 6;  // 0..3
  float4* out4 = (float4*)out;

  if (hs < 0) {
    #pragma unroll 4
    for (int oc = ocq; oc < 64; oc += 4) {
      float bv = bps[oc];
      out4[(((size_t)b * 64 + oc) * HH + h) * 64 + wq] = make_float4(bv, bv, bv, bv);
    }
    return;
  }
  const int ws0 = wsmap[wq * 4 + 0], ws1 = wsmap[wq * 4 + 1];
  const int ws2 = wsmap[wq * 4 + 2], ws3 = wsmap[wq * 4 + 3];
  #pragma unroll 4
  for (int oc = ocq; oc < 64; oc += 4) {
    float bv = bps[oc];
    size_t rbase = (((size_t)b * 64 + oc) * NS + hs) * NS;
    float4 v = make_float4(bv, bv, bv, bv);
    if (ws0 >= 0) v.x += P[rbase + ws0];
    if (ws1 >= 0) v.y += P[rbase + ws1];
    if (ws2 >= 0) v.z += P[rbase + ws2];
    if (ws3 >= 0) v.w += P[rbase + ws3];
    out4[(((size_t)b * 64 + oc) * HH + h) * 64 + wq] = v;
  }
}

extern "C" void kernel_launch(void* const* d_in, const int* in_sizes, int n_in,
                              void* d_out, int out_size, void* d_ws, size_t ws_size,
                              hipStream_t stream) {
  const float* x1 = (const float*)d_in[0];
  const float* x2 = (const float*)d_in[1];
  const float* Wk = (const float*)d_in[2];
  const float* bk = (const float*)d_in[3];
  const float* Wv = (const float*)d_in[4];
  const float* bv = (const float*)d_in[5];
  const float* Wp = (const float*)d_in[6];
  const float* bp = (const float*)d_in[7];
  float* P = (float*)d_ws;  // 8*64*84*84 floats = 14.45 MB
  float* out = (float*)d_out;

  k1_fused<<<dim3(BB * SPP), dim3(256), 0, stream>>>(x1, x2, Wk, bk, Wv, bv, Wp, P);
  k2_merge<<<dim3(BB * HH), dim3(256), 0, stream>>>(P, bp, out);
}